// Round 6
// baseline (208.450 us; speedup 1.0000x reference)
//
#include <hip/hip_runtime.h>

#define N_NODES 20000
#define DIM 128
#define N_EDGES 500000
#define BATCH 16384
#define EPS 1e-6f
#define L2E 1.4426950408889634f

typedef _Float16 half8 __attribute__((ext_vector_type(8)));
typedef _Float16 half4_t __attribute__((ext_vector_type(4)));
typedef float f32x4 __attribute__((ext_vector_type(4)));
typedef float f32x2 __attribute__((ext_vector_type(2)));

__device__ __forceinline__ float fast_sqrtf(float x) {
#if __has_builtin(__builtin_amdgcn_sqrtf)
    return __builtin_amdgcn_sqrtf(x);
#else
    return sqrtf(x);
#endif
}
__device__ __forceinline__ float fast_exp2f(float x) {
#if __has_builtin(__builtin_amdgcn_exp2f)
    return __builtin_amdgcn_exp2f(x);
#else
    return exp2f(x);
#endif
}

#define NB_TILE 8256               // 129*64 wrapped-triangle 128x128 tiles
#define NB_STEP 16512              // 2 steps (64-col halves) per tile
#define N_BLK   512                // persistent blocks; contiguous runs of steps

// ---- workspace layout (bytes) ----
#define OFF_PGEMM 0                // N_BLK*4 = 2048
#define OFF_CTR   16384            // done-counter (4B), zeroed by prep
#define OFF_PSH   33280            // A: gathered p_star rows fp16, chunk-swizzled (16384*128*2)
#define OFF_PPH   4227584          // B: gathered p rows fp16, chunk-swizzled
#define OFF_N2S   8421888
#define OFF_N2P   8487424
#define OFF_BPS   8552960          // L2E * beta_p_star gathered
#define OFF_BP    8618496          // L2E * beta_p gathered
#define OFF_END   8684032

// Prep: gather rows -> fp16 with per-row XOR chunk swizzle (so main can stage
// with linear global_load_lds and read conflict-free), + norms + L2E*beta.
// Physical 16B chunk pc within a row holds logical chunk lc where
// pc = (h<<3) | ((lc&7) ^ (row&7)), h = lc>>3 (K-half preserved).
__global__ __launch_bounds__(256) void prep_kernel(
    const float* __restrict__ p, const float* __restrict__ p_star,
    const float* __restrict__ beta_p, const float* __restrict__ beta_ps,
    const int* __restrict__ nodes_ps, const int* __restrict__ nodes_p,
    _Float16* __restrict__ Ah, float* __restrict__ n2A, float* __restrict__ bA2,
    _Float16* __restrict__ Bh, float* __restrict__ n2B, float* __restrict__ bB2,
    unsigned* __restrict__ ctr)
{
    if (blockIdx.x == 0 && threadIdx.x == 0) *ctr = 0u;   // reset done-counter
    const int bx = blockIdx.x;
    const int g = threadIdx.x & 31;
    const int r8 = threadIdx.x >> 5;
    const bool isA = bx < 2048;
    const int row = (isA ? bx : bx - 2048) * 8 + r8;
    const int id = isA ? nodes_ps[row] : nodes_p[row];
    const float* src = isA ? p_star : p;
    float4 v = ((const float4*)(src + (size_t)id * DIM))[g];
    half4_t o;
    o[0] = (_Float16)v.x; o[1] = (_Float16)v.y; o[2] = (_Float16)v.z; o[3] = (_Float16)v.w;
    const int h = g >> 4;                      // K-half
    const int pc = ((g >> 1) & 7) ^ (row & 7); // swizzled in-half chunk
    _Float16* dst = isA ? Ah : Bh;
    *(half4_t*)(dst + (size_t)row * DIM + (((h << 3) | pc) << 3) + (g & 1) * 4) = o;
    float nrm = v.x * v.x + v.y * v.y + v.z * v.z + v.w * v.w;
    #pragma unroll
    for (int m = 16; m >= 1; m >>= 1) nrm += __shfl_xor(nrm, m, 32);
    if (g == 0) {
        if (isA) { n2A[row] = nrm; bA2[row] = L2E * beta_ps[id]; }
        else     { n2B[row] = nrm; bB2[row] = L2E * beta_p[id]; }
    }
}

// map wrapped-triangle tile index -> (i0, tj*128, diag)
__device__ __forceinline__ void tile_of(int t, int& i0, int& tjb, bool& diag) {
    const int by = t / 129;
    const int bx = t - by * 129;
    const int len = 128 - by;
    int ti, tj;
    if (bx < len) { ti = by; tj = by + bx; }
    else          { ti = 127 - by; tj = 127 - (bx - len); }
    i0 = ti << 7; tjb = tj << 7; diag = (ti == tj);
}

// LDS map (bytes): A [2 khalf][128 rows][64 cols] fp16 = 32768
//                  B [2 khalf][ 64 rows][64 cols] fp16 = 16384 at +32768
// K-half-major, 128B row stride -> conflict-free ds_read_b128 (rounds 1-5).
// Each DMA instr: 64 lanes x 16B = 8 rows x 8 chunks, wave-uniform LDS base.
#define STAGE_A(I0)                                                                \
    {                                                                              \
        _Pragma("unroll")                                                          \
        for (int u = 0; u < 4; ++u) {                                              \
            const int g8 = u * 8 + w;            /* 0..31 */                       \
            const int h = g8 >> 4, rg = g8 & 15;                                   \
            __builtin_amdgcn_global_load_lds(                                      \
                (const __attribute__((address_space(1))) void*)(gA +               \
                    (((size_t)((I0) + rg * 8 + (lane >> 3))) << 8)                 \
                    + (h << 7) + ((lane & 7) << 4)),                               \
                (__attribute__((address_space(3))) void*)(lds                      \
                    + h * 16384 + rg * 1024), 16, 0, 0);                           \
        }                                                                          \
    }

#define STAGE_B(JB)                                                                \
    {                                                                              \
        _Pragma("unroll")                                                          \
        for (int u = 0; u < 2; ++u) {                                              \
            const int g8 = u * 8 + w;            /* 0..15 */                       \
            const int h = g8 >> 3, rg = g8 & 7;                                    \
            __builtin_amdgcn_global_load_lds(                                      \
                (const __attribute__((address_space(1))) void*)(gB +               \
                    (((size_t)((JB) + rg * 8 + (lane >> 3))) << 8)                 \
                    + (h << 7) + ((lane & 7) << 4)),                               \
                (__attribute__((address_space(3))) void*)(lds + 32768              \
                    + h * 8192 + rg * 1024), 16, 0, 0);                            \
        }                                                                          \
    }

// Main: N_BLK persistent blocks of 512 threads, contiguous runs of 128x64
// steps. A panel resident across a row-band; B half restages per step under
// the link+epilogue compute. 8 waves x 32x32 subtiles. Last block reduces.
__global__ __launch_bounds__(512, 6) void main_kernel(
    const _Float16* __restrict__ Ag, const _Float16* __restrict__ Bg,
    const float* __restrict__ n2A, const float* __restrict__ n2B,
    const float* __restrict__ bA2, const float* __restrict__ bB2,
    const int* __restrict__ edges,
    const float* __restrict__ beta_p, const float* __restrict__ beta_ps,
    const float* __restrict__ pf, const float* __restrict__ psf,
    float* __restrict__ pgemm, unsigned* __restrict__ ctr,
    float* __restrict__ out)
{
    __shared__ __align__(16) _Float16 sm16[24576];  // 48 KiB: A 16K halves, B 8K
    __shared__ float smr[8];
    __shared__ int lastflag;

    const int b = blockIdx.x;
    const int tid = threadIdx.x;
    const int lane = tid & 63;
    const int w = tid >> 6;       // 0..7
    const int wm = w & 3;         // 32-row quarter of the 128-row tile
    const int wn = w >> 2;        // 32-col half of the 64-col step
    const int quad = lane >> 4;
    const int lr = lane & 15;
    const int k7 = lr & 7;        // read-side swizzle key (== row&7 of frag rows)

    auto* lds = (__attribute__((address_space(3))) char*)sm16;
    const auto* gA = (const __attribute__((address_space(1))) char*)Ag;
    const auto* gB = (const __attribute__((address_space(1))) char*)Bg;

    float lsum = 0.f;
    f32x2 lacc = {0.f, 0.f};

    // contiguous runs: first 128 blocks get 33 steps, rest 32 (128*33+384*32=16512)
    const int start = b * 32 + (b < 128 ? b : 128);
    const int tend = start + 32 + (b < 128 ? 1 : 0);

    int s = start;
    int i0, tjb; bool diag;
    {
        tile_of(s >> 1, i0, tjb, diag);
        const int hb = s & 1;
        STAGE_A(i0)
        STAGE_B(tjb + hb * 64)
    }
    __syncthreads();   // prologue step ready

    for (;;) {
        const int hb = s & 1;
        // wave class: rows [wm*32,+32) vs cols 32-block cj of the 128-tile
        int cls = 0;  // 0=free (all j>i), 1=masked, 2=dead
        if (diag) { const int cj = hb * 2 + wn; cls = (cj > wm) ? 0 : (cj == wm ? 1 : 2); }

        f32x4 acc[2][2] = {};
        if (cls != 2) {
            #pragma unroll
            for (int ks = 0; ks < 4; ++ks) {
                const int h = ks >> 1;
                const int pc = (((ks & 1) << 2) | quad) ^ k7;   // (lc&7)^k7
                half8 af[2], bf[2];
                #pragma unroll
                for (int u = 0; u < 2; ++u)
                    af[u] = *(const half8*)&sm16[h * 8192 + (wm * 32 + u * 16 + lr) * 64 + pc * 8];
                #pragma unroll
                for (int v = 0; v < 2; ++v)
                    bf[v] = *(const half8*)&sm16[16384 + h * 4096 + (wn * 32 + v * 16 + lr) * 64 + pc * 8];
                #pragma unroll
                for (int mi = 0; mi < 2; ++mi)
                    #pragma unroll
                    for (int ni = 0; ni < 2; ++ni)
                        acc[mi][ni] = __builtin_amdgcn_mfma_f32_16x16x32_f16(
                            af[mi], bf[ni], acc[mi][ni], 0, 0, 0);
            }
        }

        const int ilo = i0 + wm * 32;
        const int jlo = tjb + hb * 64 + wn * 32;
        const int scur = s;
        __syncthreads();                 // WAR: all LDS reads of this step done

        s += 1;
        const bool more = (s < tend);
        if (more) {
            const int pi0 = i0;
            tile_of(s >> 1, i0, tjb, diag);
            if (i0 != pi0) STAGE_A(i0)   // row-band changed (few times per block)
            STAGE_B(tjb + (s & 1) * 64)  // async; lands under link+epilogue
        }

        // ---- link edges of step scur: fp32, exact reference math ----
        #pragma unroll
        for (int tt = 0; tt < 1; ++tt) {
            int e = scur * 32 + w * 4 + quad;
            if (e < N_EDGES) {
                int e0 = edges[e];
                int e1 = edges[N_EDGES + e];
                const float* ar = pf + (size_t)e0 * DIM + lr * 8;
                const float* br = psf + (size_t)e1 * DIM + lr * 8;
                f32x4 a0 = *(const f32x4*)ar;   f32x4 a1 = *(const f32x4*)(ar + 4);
                f32x4 b0 = *(const f32x4*)br;   f32x4 b1 = *(const f32x4*)(br + 4);
                float eb2 = (lr == 0) ? (beta_ps[e0] + beta_p[e1]) : 0.f;
                float ssum = 0.f;
                #pragma unroll
                for (int k = 0; k < 4; ++k) { float d = a0[k] - b0[k] + EPS; ssum = fmaf(d, d, ssum); }
                #pragma unroll
                for (int k = 0; k < 4; ++k) { float d = a1[k] - b1[k] + EPS; ssum = fmaf(d, d, ssum); }
                #pragma unroll
                for (int m = 8; m >= 1; m >>= 1) ssum += __shfl_xor(ssum, m, 16);
                if (lr == 0) lsum -= eb2 - fast_sqrtf(ssum);
            }
        }

        // ---- epilogue (covers next step's staging latency); f32x2-packed ----
        if (cls != 2) {
            f32x4 n2i[2], bi[2];
            #pragma unroll
            for (int mi = 0; mi < 2; ++mi) {
                n2i[mi] = *(const f32x4*)&n2A[ilo + mi * 16 + quad * 4];
                bi[mi]  = *(const f32x4*)&bA2[ilo + mi * 16 + quad * 4];
            }
            float n2j[2], bj[2];
            #pragma unroll
            for (int ni = 0; ni < 2; ++ni) {
                n2j[ni] = n2B[jlo + ni * 16 + lr];
                bj[ni]  = bB2[jlo + ni * 16 + lr];
            }

            // C/D layout: col = lane&15, row = quad*4 + reg
            #pragma unroll
            for (int mi = 0; mi < 2; ++mi)
                #pragma unroll
                for (int ni = 0; ni < 2; ++ni) {
                    const f32x4 d = acc[mi][ni];
                    #pragma unroll
                    for (int pr = 0; pr < 2; ++pr) {
                        f32x2 d2 = { d[2 * pr], d[2 * pr + 1] };
                        f32x2 t2 = { n2i[mi][2 * pr] + n2j[ni], n2i[mi][2 * pr + 1] + n2j[ni] };
                        f32x2 sq2 = d2 * -2.0f + t2;
                        f32x2 z2 = { 0.f, 0.f };
                        f32x2 mx2 = __builtin_elementwise_max(sq2, z2);
                        float s0 = fast_sqrtf(mx2[0]);
                        float s1 = fast_sqrtf(mx2[1]);
                        f32x2 bs2 = { bi[mi][2 * pr] + bj[ni], bi[mi][2 * pr + 1] + bj[ni] };
                        f32x2 sr2 = { s0, s1 };
                        f32x2 ar2 = sr2 * -L2E + bs2;
                        float e0 = fast_exp2f(ar2[0]);
                        float e1 = fast_exp2f(ar2[1]);
                        if (cls == 0) {
                            f32x2 e2 = { e0, e1 };
                            lacc += e2;
                        } else {
                            const int ig0 = ilo + mi * 16 + quad * 4 + 2 * pr;
                            const int jg = jlo + ni * 16 + lr;
                            if (jg > ig0)     lacc[0] += e0;
                            if (jg > ig0 + 1) lacc[1] += e1;
                        }
                    }
                }
        }

        if (!more) break;
        __syncthreads();                 // staged step ready (vmcnt drained)
    }

    lsum += lacc[0] + lacc[1];
    #pragma unroll
    for (int m = 32; m >= 1; m >>= 1) lsum += __shfl_xor(lsum, m, 64);
    if (lane == 0) smr[w] = lsum;
    __syncthreads();
    if (tid == 0) {
        float ssum = 0.f;
        #pragma unroll
        for (int i = 0; i < 8; ++i) ssum += smr[i];
        pgemm[b] = ssum;
        // release the partial, then count in (agent scope)
        unsigned prev = __hip_atomic_fetch_add(ctr, 1u, __ATOMIC_ACQ_REL,
                                               __HIP_MEMORY_SCOPE_AGENT);
        lastflag = (prev == N_BLK - 1) ? 1 : 0;
    }
    __syncthreads();

    if (lastflag) {
        // last block: deterministic fixed-order reduction of N_BLK partials
        float v = __hip_atomic_load(&pgemm[tid], __ATOMIC_RELAXED,
                                    __HIP_MEMORY_SCOPE_AGENT);
        #pragma unroll
        for (int m = 32; m >= 1; m >>= 1) v += __shfl_xor(v, m, 64);
        if (lane == 0) smr[w] = v;
        __syncthreads();
        if (tid == 0) {
            float tsum = 0.f;
            #pragma unroll
            for (int i = 0; i < 8; ++i) tsum += smr[i];
            out[0] = tsum;
        }
    }
}

extern "C" void kernel_launch(void* const* d_in, const int* in_sizes, int n_in,
                              void* d_out, int out_size, void* d_ws, size_t ws_size,
                              hipStream_t stream) {
    const int* edges = (const int*)d_in[0];
    const int* nodes_p_star = (const int*)d_in[1];
    const int* nodes_p = (const int*)d_in[2];
    const float* beta_p = (const float*)d_in[3];
    const float* beta_p_star = (const float*)d_in[4];
    const float* p = (const float*)d_in[5];
    const float* p_star = (const float*)d_in[6];

    char* ws = (char*)d_ws;
    float* pgemm = (float*)(ws + OFF_PGEMM);
    unsigned* ctr = (unsigned*)(ws + OFF_CTR);
    _Float16* psh = (_Float16*)(ws + OFF_PSH);
    _Float16* pph = (_Float16*)(ws + OFF_PPH);
    float* n2s = (float*)(ws + OFF_N2S);
    float* n2p = (float*)(ws + OFF_N2P);
    float* bps2 = (float*)(ws + OFF_BPS);
    float* bp2 = (float*)(ws + OFF_BP);

    prep_kernel<<<4096, 256, 0, stream>>>(
        p, p_star, beta_p, beta_p_star, nodes_p_star, nodes_p,
        psh, n2s, bps2, pph, n2p, bp2, ctr);

    main_kernel<<<N_BLK, 512, 0, stream>>>(
        psh, pph, n2s, n2p, bps2, bp2,
        edges, beta_p, beta_p_star, p, p_star,
        pgemm, ctr, (float*)d_out);
}

// Round 7
// 205.289 us; speedup vs baseline: 1.0154x; 1.0154x over previous
//
#include <hip/hip_runtime.h>

#define N_NODES 20000
#define DIM 128
#define N_EDGES 500000
#define BATCH 16384
#define EPS 1e-6f
#define L2E 1.4426950408889634f

typedef _Float16 half8 __attribute__((ext_vector_type(8)));
typedef _Float16 half4_t __attribute__((ext_vector_type(4)));
typedef float f32x4 __attribute__((ext_vector_type(4)));
typedef float f32x2 __attribute__((ext_vector_type(2)));

__device__ __forceinline__ float fast_sqrtf(float x) {
#if __has_builtin(__builtin_amdgcn_sqrtf)
    return __builtin_amdgcn_sqrtf(x);
#else
    return sqrtf(x);
#endif
}
__device__ __forceinline__ float fast_exp2f(float x) {
#if __has_builtin(__builtin_amdgcn_exp2f)
    return __builtin_amdgcn_exp2f(x);
#else
    return exp2f(x);
#endif
}

#define NB_TILE 8256               // 129*64 wrapped-triangle 128x128 tiles
#define NB_STEP 16512              // 2 steps (64-col halves) per tile
#define N_BLK   768                // persistent blocks -> 3 blocks/CU resident

// ---- workspace layout (bytes) ----
#define OFF_PGEMM 0                // N_BLK*4 = 3072
#define OFF_CTR   16384            // done-counter (4B), zeroed by prep
#define OFF_PSH   33280            // A: gathered p_star rows fp16, chunk-swizzled (16384*128*2)
#define OFF_PPH   4227584          // B: gathered p rows fp16, chunk-swizzled
#define OFF_N2S   8421888
#define OFF_N2P   8487424
#define OFF_BPS   8552960          // L2E * beta_p_star gathered
#define OFF_BP    8618496          // L2E * beta_p gathered
#define OFF_END   8684032

// Prep: gather rows -> fp16 with per-row XOR chunk swizzle (so main can stage
// with linear global_load_lds and read conflict-free), + norms + L2E*beta.
// Physical 16B chunk pc within a row holds logical chunk lc where
// pc = (h<<3) | ((lc&7) ^ (row&7)), h = lc>>3 (K-half preserved).
__global__ __launch_bounds__(256) void prep_kernel(
    const float* __restrict__ p, const float* __restrict__ p_star,
    const float* __restrict__ beta_p, const float* __restrict__ beta_ps,
    const int* __restrict__ nodes_ps, const int* __restrict__ nodes_p,
    _Float16* __restrict__ Ah, float* __restrict__ n2A, float* __restrict__ bA2,
    _Float16* __restrict__ Bh, float* __restrict__ n2B, float* __restrict__ bB2,
    unsigned* __restrict__ ctr)
{
    if (blockIdx.x == 0 && threadIdx.x == 0) *ctr = 0u;   // reset done-counter
    const int bx = blockIdx.x;
    const int g = threadIdx.x & 31;
    const int r8 = threadIdx.x >> 5;
    const bool isA = bx < 2048;
    const int row = (isA ? bx : bx - 2048) * 8 + r8;
    const int id = isA ? nodes_ps[row] : nodes_p[row];
    const float* src = isA ? p_star : p;
    float4 v = ((const float4*)(src + (size_t)id * DIM))[g];
    half4_t o;
    o[0] = (_Float16)v.x; o[1] = (_Float16)v.y; o[2] = (_Float16)v.z; o[3] = (_Float16)v.w;
    const int h = g >> 4;                      // K-half
    const int pc = ((g >> 1) & 7) ^ (row & 7); // swizzled in-half chunk
    _Float16* dst = isA ? Ah : Bh;
    *(half4_t*)(dst + (size_t)row * DIM + (((h << 3) | pc) << 3) + (g & 1) * 4) = o;
    float nrm = v.x * v.x + v.y * v.y + v.z * v.z + v.w * v.w;
    #pragma unroll
    for (int m = 16; m >= 1; m >>= 1) nrm += __shfl_xor(nrm, m, 32);
    if (g == 0) {
        if (isA) { n2A[row] = nrm; bA2[row] = L2E * beta_ps[id]; }
        else     { n2B[row] = nrm; bB2[row] = L2E * beta_p[id]; }
    }
}

// map wrapped-triangle tile index -> (i0, tj*128, diag)
__device__ __forceinline__ void tile_of(int t, int& i0, int& tjb, bool& diag) {
    const int by = t / 129;
    const int bx = t - by * 129;
    const int len = 128 - by;
    int ti, tj;
    if (bx < len) { ti = by; tj = by + bx; }
    else          { ti = 127 - by; tj = 127 - (bx - len); }
    i0 = ti << 7; tjb = tj << 7; diag = (ti == tj);
}

// LDS map (bytes): A [2 khalf][128 rows][64 cols] fp16 = 32768
//                  B [2 khalf][ 64 rows][64 cols] fp16 = 16384 at +32768
// K-half-major, 128B row stride -> conflict-free ds_read_b128 (rounds 1-5).
// Each DMA instr: 64 lanes x 16B = 8 rows x 8 chunks, wave-uniform LDS base.
#define STAGE_A(I0)                                                                \
    {                                                                              \
        _Pragma("unroll")                                                          \
        for (int u = 0; u < 4; ++u) {                                              \
            const int g8 = u * 8 + w;            /* 0..31 */                       \
            const int h = g8 >> 4, rg = g8 & 15;                                   \
            __builtin_amdgcn_global_load_lds(                                      \
                (const __attribute__((address_space(1))) void*)(gA +               \
                    (((size_t)((I0) + rg * 8 + (lane >> 3))) << 8)                 \
                    + (h << 7) + ((lane & 7) << 4)),                               \
                (__attribute__((address_space(3))) void*)(lds                      \
                    + h * 16384 + rg * 1024), 16, 0, 0);                           \
        }                                                                          \
    }

#define STAGE_B(JB)                                                                \
    {                                                                              \
        _Pragma("unroll")                                                          \
        for (int u = 0; u < 2; ++u) {                                              \
            const int g8 = u * 8 + w;            /* 0..15 */                       \
            const int h = g8 >> 3, rg = g8 & 7;                                    \
            __builtin_amdgcn_global_load_lds(                                      \
                (const __attribute__((address_space(1))) void*)(gB +               \
                    (((size_t)((JB) + rg * 8 + (lane >> 3))) << 8)                 \
                    + (h << 7) + ((lane & 7) << 4)),                               \
                (__attribute__((address_space(3))) void*)(lds + 32768              \
                    + h * 8192 + rg * 1024), 16, 0, 0);                            \
        }                                                                          \
    }

// Main: N_BLK persistent blocks of 512 threads, contiguous runs of 128x64
// steps. A panel resident across a row-band; B half restages per step under
// the link+epilogue compute. 8 waves x 32x32 subtiles. Last block reduces.
__global__ __launch_bounds__(512, 6) void main_kernel(
    const _Float16* __restrict__ Ag, const _Float16* __restrict__ Bg,
    const float* __restrict__ n2A, const float* __restrict__ n2B,
    const float* __restrict__ bA2, const float* __restrict__ bB2,
    const int* __restrict__ edges,
    const float* __restrict__ beta_p, const float* __restrict__ beta_ps,
    const float* __restrict__ pf, const float* __restrict__ psf,
    float* __restrict__ pgemm, unsigned* __restrict__ ctr,
    float* __restrict__ out)
{
    __shared__ __align__(16) _Float16 sm16[24576];  // 48 KiB: A 16K halves, B 8K
    __shared__ float smr[8];
    __shared__ int lastflag;

    const int b = blockIdx.x;
    const int tid = threadIdx.x;
    const int lane = tid & 63;
    const int w = tid >> 6;       // 0..7
    const int wm = w & 3;         // 32-row quarter of the 128-row tile
    const int wn = w >> 2;        // 32-col half of the 64-col step
    const int quad = lane >> 4;
    const int lr = lane & 15;
    const int k7 = lr & 7;        // read-side swizzle key (== row&7 of frag rows)

    auto* lds = (__attribute__((address_space(3))) char*)sm16;
    const auto* gA = (const __attribute__((address_space(1))) char*)Ag;
    const auto* gB = (const __attribute__((address_space(1))) char*)Bg;

    float lsum = 0.f;
    f32x2 lacc = {0.f, 0.f};

    // contiguous runs: first 384 blocks get 22 steps, rest 21 (384*22+384*21=16512)
    const int start = b * 21 + (b < 384 ? b : 384);
    const int tend = start + 21 + (b < 384 ? 1 : 0);

    int s = start;
    int i0, tjb; bool diag;
    {
        tile_of(s >> 1, i0, tjb, diag);
        const int hb = s & 1;
        STAGE_A(i0)
        STAGE_B(tjb + hb * 64)
    }
    __syncthreads();   // prologue step ready

    for (;;) {
        const int hb = s & 1;
        // wave class: rows [wm*32,+32) vs cols 32-block cj of the 128-tile
        int cls = 0;  // 0=free (all j>i), 1=masked, 2=dead
        if (diag) { const int cj = hb * 2 + wn; cls = (cj > wm) ? 0 : (cj == wm ? 1 : 2); }

        f32x4 acc[2][2] = {};
        if (cls != 2) {
            #pragma unroll
            for (int ks = 0; ks < 4; ++ks) {
                const int h = ks >> 1;
                const int pc = (((ks & 1) << 2) | quad) ^ k7;   // (lc&7)^k7
                half8 af[2], bf[2];
                #pragma unroll
                for (int u = 0; u < 2; ++u)
                    af[u] = *(const half8*)&sm16[h * 8192 + (wm * 32 + u * 16 + lr) * 64 + pc * 8];
                #pragma unroll
                for (int v = 0; v < 2; ++v)
                    bf[v] = *(const half8*)&sm16[16384 + h * 4096 + (wn * 32 + v * 16 + lr) * 64 + pc * 8];
                #pragma unroll
                for (int mi = 0; mi < 2; ++mi)
                    #pragma unroll
                    for (int ni = 0; ni < 2; ++ni)
                        acc[mi][ni] = __builtin_amdgcn_mfma_f32_16x16x32_f16(
                            af[mi], bf[ni], acc[mi][ni], 0, 0, 0);
            }
        }

        const int ilo = i0 + wm * 32;
        const int jlo = tjb + hb * 64 + wn * 32;
        const int scur = s;
        __syncthreads();                 // WAR: all LDS reads of this step done

        s += 1;
        const bool more = (s < tend);
        if (more) {
            const int pi0 = i0;
            tile_of(s >> 1, i0, tjb, diag);
            if (i0 != pi0) STAGE_A(i0)   // row-band changed (few times per block)
            STAGE_B(tjb + (s & 1) * 64)  // async; lands under link+epilogue
        }

        // ---- link edges of step scur: fp32, exact reference math ----
        {
            int e = scur * 32 + w * 4 + quad;
            if (e < N_EDGES) {
                int e0 = edges[e];
                int e1 = edges[N_EDGES + e];
                const float* ar = pf + (size_t)e0 * DIM + lr * 8;
                const float* br = psf + (size_t)e1 * DIM + lr * 8;
                f32x4 a0 = *(const f32x4*)ar;   f32x4 a1 = *(const f32x4*)(ar + 4);
                f32x4 b0 = *(const f32x4*)br;   f32x4 b1 = *(const f32x4*)(br + 4);
                float eb2 = (lr == 0) ? (beta_ps[e0] + beta_p[e1]) : 0.f;
                float ssum = 0.f;
                #pragma unroll
                for (int k = 0; k < 4; ++k) { float d = a0[k] - b0[k] + EPS; ssum = fmaf(d, d, ssum); }
                #pragma unroll
                for (int k = 0; k < 4; ++k) { float d = a1[k] - b1[k] + EPS; ssum = fmaf(d, d, ssum); }
                #pragma unroll
                for (int m = 8; m >= 1; m >>= 1) ssum += __shfl_xor(ssum, m, 16);
                if (lr == 0) lsum -= eb2 - fast_sqrtf(ssum);
            }
        }

        // ---- epilogue (covers next step's staging latency); f32x2-packed ----
        if (cls != 2) {
            f32x4 n2i[2], bi[2];
            #pragma unroll
            for (int mi = 0; mi < 2; ++mi) {
                n2i[mi] = *(const f32x4*)&n2A[ilo + mi * 16 + quad * 4];
                bi[mi]  = *(const f32x4*)&bA2[ilo + mi * 16 + quad * 4];
            }
            float n2j[2], bj[2];
            #pragma unroll
            for (int ni = 0; ni < 2; ++ni) {
                n2j[ni] = n2B[jlo + ni * 16 + lr];
                bj[ni]  = bB2[jlo + ni * 16 + lr];
            }

            // C/D layout: col = lane&15, row = quad*4 + reg
            #pragma unroll
            for (int mi = 0; mi < 2; ++mi)
                #pragma unroll
                for (int ni = 0; ni < 2; ++ni) {
                    const f32x4 d = acc[mi][ni];
                    #pragma unroll
                    for (int pr = 0; pr < 2; ++pr) {
                        f32x2 d2 = { d[2 * pr], d[2 * pr + 1] };
                        f32x2 t2 = { n2i[mi][2 * pr] + n2j[ni], n2i[mi][2 * pr + 1] + n2j[ni] };
                        f32x2 sq2 = d2 * -2.0f + t2;
                        f32x2 z2 = { 0.f, 0.f };
                        f32x2 mx2 = __builtin_elementwise_max(sq2, z2);
                        float s0 = fast_sqrtf(mx2[0]);
                        float s1 = fast_sqrtf(mx2[1]);
                        f32x2 bs2 = { bi[mi][2 * pr] + bj[ni], bi[mi][2 * pr + 1] + bj[ni] };
                        f32x2 sr2 = { s0, s1 };
                        f32x2 ar2 = sr2 * -L2E + bs2;
                        float e0 = fast_exp2f(ar2[0]);
                        float e1 = fast_exp2f(ar2[1]);
                        if (cls == 0) {
                            f32x2 e2 = { e0, e1 };
                            lacc += e2;
                        } else {
                            const int ig0 = ilo + mi * 16 + quad * 4 + 2 * pr;
                            const int jg = jlo + ni * 16 + lr;
                            if (jg > ig0)     lacc[0] += e0;
                            if (jg > ig0 + 1) lacc[1] += e1;
                        }
                    }
                }
        }

        if (!more) break;
        __syncthreads();                 // staged step ready (vmcnt drained)
    }

    lsum += lacc[0] + lacc[1];
    #pragma unroll
    for (int m = 32; m >= 1; m >>= 1) lsum += __shfl_xor(lsum, m, 64);
    if (lane == 0) smr[w] = lsum;
    __syncthreads();
    if (tid == 0) {
        float ssum = 0.f;
        #pragma unroll
        for (int i = 0; i < 8; ++i) ssum += smr[i];
        pgemm[b] = ssum;
        // release the partial, then count in (agent scope)
        unsigned prev = __hip_atomic_fetch_add(ctr, 1u, __ATOMIC_ACQ_REL,
                                               __HIP_MEMORY_SCOPE_AGENT);
        lastflag = (prev == N_BLK - 1) ? 1 : 0;
    }
    __syncthreads();

    if (lastflag) {
        // last block: deterministic fixed-order reduction of N_BLK partials
        float v = __hip_atomic_load(&pgemm[tid], __ATOMIC_RELAXED,
                                    __HIP_MEMORY_SCOPE_AGENT);
        if (tid < N_BLK - 512)
            v += __hip_atomic_load(&pgemm[tid + 512], __ATOMIC_RELAXED,
                                   __HIP_MEMORY_SCOPE_AGENT);
        #pragma unroll
        for (int m = 32; m >= 1; m >>= 1) v += __shfl_xor(v, m, 64);
        if (lane == 0) smr[w] = v;
        __syncthreads();
        if (tid == 0) {
            float tsum = 0.f;
            #pragma unroll
            for (int i = 0; i < 8; ++i) tsum += smr[i];
            out[0] = tsum;
        }
    }
}

extern "C" void kernel_launch(void* const* d_in, const int* in_sizes, int n_in,
                              void* d_out, int out_size, void* d_ws, size_t ws_size,
                              hipStream_t stream) {
    const int* edges = (const int*)d_in[0];
    const int* nodes_p_star = (const int*)d_in[1];
    const int* nodes_p = (const int*)d_in[2];
    const float* beta_p = (const float*)d_in[3];
    const float* beta_p_star = (const float*)d_in[4];
    const float* p = (const float*)d_in[5];
    const float* p_star = (const float*)d_in[6];

    char* ws = (char*)d_ws;
    float* pgemm = (float*)(ws + OFF_PGEMM);
    unsigned* ctr = (unsigned*)(ws + OFF_CTR);
    _Float16* psh = (_Float16*)(ws + OFF_PSH);
    _Float16* pph = (_Float16*)(ws + OFF_PPH);
    float* n2s = (float*)(ws + OFF_N2S);
    float* n2p = (float*)(ws + OFF_N2P);
    float* bps2 = (float*)(ws + OFF_BPS);
    float* bp2 = (float*)(ws + OFF_BP);

    prep_kernel<<<4096, 256, 0, stream>>>(
        p, p_star, beta_p, beta_p_star, nodes_p_star, nodes_p,
        psh, n2s, bps2, pph, n2p, bp2, ctr);

    main_kernel<<<N_BLK, 512, 0, stream>>>(
        psh, pph, n2s, n2p, bps2, bp2,
        edges, beta_p, beta_p_star, p, p_star,
        pgemm, ctr, (float*)d_out);
}

// Round 8
// 205.031 us; speedup vs baseline: 1.0167x; 1.0013x over previous
//
#include <hip/hip_runtime.h>

#define N_NODES 20000
#define DIM 128
#define N_EDGES 500000
#define BATCH 16384
#define EPS 1e-6f
#define L2E 1.4426950408889634f

typedef _Float16 half8 __attribute__((ext_vector_type(8)));
typedef _Float16 half4_t __attribute__((ext_vector_type(4)));
typedef float f32x4 __attribute__((ext_vector_type(4)));
typedef float f32x2 __attribute__((ext_vector_type(2)));

__device__ __forceinline__ float fast_sqrtf(float x) {
#if __has_builtin(__builtin_amdgcn_sqrtf)
    return __builtin_amdgcn_sqrtf(x);
#else
    return sqrtf(x);
#endif
}
__device__ __forceinline__ float fast_exp2f(float x) {
#if __has_builtin(__builtin_amdgcn_exp2f)
    return __builtin_amdgcn_exp2f(x);
#else
    return exp2f(x);
#endif
}

#define NB_TILE 8256               // 129*64 wrapped-triangle 128x128 tiles
#define N_BLK   512                // persistent 1024-thread blocks -> 2/CU, 32 waves/CU

// ---- workspace layout (bytes) ----
#define OFF_PGEMM 0                // N_BLK*4 = 2048
#define OFF_CTR   16384            // done-counter (4B), zeroed by prep
#define OFF_PSH   33280            // A: gathered p_star rows fp16, chunk-swizzled (16384*128*2)
#define OFF_PPH   4227584          // B: gathered p rows fp16, chunk-swizzled
#define OFF_N2S   8421888
#define OFF_N2P   8487424
#define OFF_BPS   8552960          // L2E * beta_p_star gathered
#define OFF_BP    8618496          // L2E * beta_p gathered
#define OFF_END   8684032

// Prep: gather rows -> fp16 with per-row XOR chunk swizzle (so main can stage
// with linear global_load_lds and read conflict-free), + norms + L2E*beta.
// Physical 16B chunk pc within a row holds logical chunk lc where
// pc = (h<<3) | ((lc&7) ^ (row&7)), h = lc>>3 (K-half preserved).
__global__ __launch_bounds__(256) void prep_kernel(
    const float* __restrict__ p, const float* __restrict__ p_star,
    const float* __restrict__ beta_p, const float* __restrict__ beta_ps,
    const int* __restrict__ nodes_ps, const int* __restrict__ nodes_p,
    _Float16* __restrict__ Ah, float* __restrict__ n2A, float* __restrict__ bA2,
    _Float16* __restrict__ Bh, float* __restrict__ n2B, float* __restrict__ bB2,
    unsigned* __restrict__ ctr)
{
    if (blockIdx.x == 0 && threadIdx.x == 0) *ctr = 0u;   // reset done-counter
    const int bx = blockIdx.x;
    const int g = threadIdx.x & 31;
    const int r8 = threadIdx.x >> 5;
    const bool isA = bx < 2048;
    const int row = (isA ? bx : bx - 2048) * 8 + r8;
    const int id = isA ? nodes_ps[row] : nodes_p[row];
    const float* src = isA ? p_star : p;
    float4 v = ((const float4*)(src + (size_t)id * DIM))[g];
    half4_t o;
    o[0] = (_Float16)v.x; o[1] = (_Float16)v.y; o[2] = (_Float16)v.z; o[3] = (_Float16)v.w;
    const int h = g >> 4;                      // K-half
    const int pc = ((g >> 1) & 7) ^ (row & 7); // swizzled in-half chunk
    _Float16* dst = isA ? Ah : Bh;
    *(half4_t*)(dst + (size_t)row * DIM + (((h << 3) | pc) << 3) + (g & 1) * 4) = o;
    float nrm = v.x * v.x + v.y * v.y + v.z * v.z + v.w * v.w;
    #pragma unroll
    for (int m = 16; m >= 1; m >>= 1) nrm += __shfl_xor(nrm, m, 32);
    if (g == 0) {
        if (isA) { n2A[row] = nrm; bA2[row] = L2E * beta_ps[id]; }
        else     { n2B[row] = nrm; bB2[row] = L2E * beta_p[id]; }
    }
}

// map wrapped-triangle tile index -> (i0, j0, diag)
__device__ __forceinline__ void tile_of(int t, int& i0, int& j0, bool& diag) {
    const int by = t / 129;
    const int bx = t - by * 129;
    const int len = 128 - by;
    int ti, tj;
    if (bx < len) { ti = by; tj = by + bx; }
    else          { ti = 127 - by; tj = 127 - (bx - len); }
    i0 = ti << 7; j0 = tj << 7; diag = (ti == tj);
}

// LDS map (bytes): A [2 khalf][128 rows][64 cols] fp16 = 32768
//                  B [2 khalf][128 rows][64 cols] fp16 = 32768 at +32768
// K-half-major, 128B row stride -> conflict-free ds_read_b128 (rounds 1-7).
// Each DMA instr: 64 lanes x 16B = 8 rows x 8 chunks, wave-uniform LDS base.
// 16 waves (w=0..15): u=0..1 covers the 32 row-group/half slots per array.
#define STAGE_ARR(BASE0, GSRC, LOFF)                                               \
    {                                                                              \
        _Pragma("unroll")                                                          \
        for (int u = 0; u < 2; ++u) {                                              \
            const int g8 = u * 16 + w;           /* 0..31 */                       \
            const int h = g8 >> 4, rg = g8 & 15;                                   \
            __builtin_amdgcn_global_load_lds(                                      \
                (const __attribute__((address_space(1))) void*)((GSRC) +           \
                    (((size_t)((BASE0) + rg * 8 + (lane >> 3))) << 8)              \
                    + (h << 7) + ((lane & 7) << 4)),                               \
                (__attribute__((address_space(3))) void*)(lds + (LOFF)             \
                    + h * 16384 + rg * 1024), 16, 0, 0);                           \
        }                                                                          \
    }

#define STAGE_A(I0) STAGE_ARR(I0, gA, 0)
#define STAGE_B(J0) STAGE_ARR(J0, gB, 32768)

// Main: N_BLK persistent 1024-thread blocks (16 waves, 4x4 grid of 32x32
// subtiles over a 128x128 tile). Per tile: compute -> WAR barrier -> issue
// next tile's async stage (B always; A on row-band change) -> link edges +
// epilogue (covers staging latency) -> barrier. Last block reduces.
__global__ __launch_bounds__(1024, 8) void main_kernel(
    const _Float16* __restrict__ Ag, const _Float16* __restrict__ Bg,
    const float* __restrict__ n2A, const float* __restrict__ n2B,
    const float* __restrict__ bA2, const float* __restrict__ bB2,
    const int* __restrict__ edges,
    const float* __restrict__ beta_p, const float* __restrict__ beta_ps,
    const float* __restrict__ pf, const float* __restrict__ psf,
    float* __restrict__ pgemm, unsigned* __restrict__ ctr,
    float* __restrict__ out)
{
    __shared__ __align__(16) _Float16 sm16[32768];  // 64 KiB: A 32K, B 32K
    __shared__ float smr[16];
    __shared__ int lastflag;

    const int b = blockIdx.x;
    const int tid = threadIdx.x;
    const int lane = tid & 63;
    const int w = tid >> 6;       // 0..15
    const int wm = w & 3;         // 32-row band of the 128-row tile
    const int wn = w >> 2;        // 32-col band of the 128-col tile
    const int quad = lane >> 4;
    const int lr = lane & 15;
    const int k7 = lr & 7;        // read-side swizzle key (== row&7 of frag rows)

    auto* lds = (__attribute__((address_space(3))) char*)sm16;
    const auto* gA = (const __attribute__((address_space(1))) char*)Ag;
    const auto* gB = (const __attribute__((address_space(1))) char*)Bg;

    float lsum = 0.f;
    f32x2 lacc = {0.f, 0.f};

    // contiguous runs: first 64 blocks get 17 tiles, rest 16 (64*17+448*16=8256)
    const int start = b * 16 + (b < 64 ? b : 64);
    const int tend = start + 16 + (b < 64 ? 1 : 0);

    int t = start;
    int i0, j0; bool diag;
    tile_of(t, i0, j0, diag);
    STAGE_A(i0)
    STAGE_B(j0)
    __syncthreads();   // prologue tile ready

    for (;;) {
        // wave class: rows [wm*32,+32) vs cols [wn*32,+32)
        int cls = 0;  // 0=free (all j>i), 1=masked, 2=dead
        if (diag) cls = (wn > wm) ? 0 : (wn == wm ? 1 : 2);

        f32x4 acc[2][2] = {};
        if (cls != 2) {
            #pragma unroll
            for (int ks = 0; ks < 4; ++ks) {
                const int h = ks >> 1;
                const int pc = (((ks & 1) << 2) | quad) ^ k7;   // (lc&7)^k7
                half8 af[2], bf[2];
                #pragma unroll
                for (int u = 0; u < 2; ++u)
                    af[u] = *(const half8*)&sm16[h * 8192 + (wm * 32 + u * 16 + lr) * 64 + pc * 8];
                #pragma unroll
                for (int v = 0; v < 2; ++v)
                    bf[v] = *(const half8*)&sm16[16384 + h * 8192 + (wn * 32 + v * 16 + lr) * 64 + pc * 8];
                #pragma unroll
                for (int mi = 0; mi < 2; ++mi)
                    #pragma unroll
                    for (int ni = 0; ni < 2; ++ni)
                        acc[mi][ni] = __builtin_amdgcn_mfma_f32_16x16x32_f16(
                            af[mi], bf[ni], acc[mi][ni], 0, 0, 0);
            }
        }

        const int ilo = i0 + wm * 32;
        const int jlo = j0 + wn * 32;
        const int tcur = t;
        __syncthreads();                 // WAR: all LDS reads of this tile done

        t += 1;
        const bool more = (t < tend);
        if (more) {
            const int pi0 = i0;
            tile_of(t, i0, j0, diag);
            if (i0 != pi0) STAGE_A(i0)   // row-band changed (rare per block)
            STAGE_B(j0)                  // async; lands under link+epilogue
        }

        // ---- link edges of tile tcur: fp32, exact reference math ----
        {
            int e = tcur * 64 + w * 4 + quad;
            if (e < N_EDGES) {
                int e0 = edges[e];
                int e1 = edges[N_EDGES + e];
                const float* ar = pf + (size_t)e0 * DIM + lr * 8;
                const float* br = psf + (size_t)e1 * DIM + lr * 8;
                f32x4 a0 = *(const f32x4*)ar;   f32x4 a1 = *(const f32x4*)(ar + 4);
                f32x4 b0 = *(const f32x4*)br;   f32x4 b1 = *(const f32x4*)(br + 4);
                float eb2 = (lr == 0) ? (beta_ps[e0] + beta_p[e1]) : 0.f;
                float ssum = 0.f;
                #pragma unroll
                for (int k = 0; k < 4; ++k) { float d = a0[k] - b0[k] + EPS; ssum = fmaf(d, d, ssum); }
                #pragma unroll
                for (int k = 0; k < 4; ++k) { float d = a1[k] - b1[k] + EPS; ssum = fmaf(d, d, ssum); }
                #pragma unroll
                for (int m = 8; m >= 1; m >>= 1) ssum += __shfl_xor(ssum, m, 16);
                if (lr == 0) lsum -= eb2 - fast_sqrtf(ssum);
            }
        }

        // ---- epilogue (covers next tile's staging latency); f32x2-packed ----
        if (cls != 2) {
            f32x4 n2i[2], bi[2];
            #pragma unroll
            for (int mi = 0; mi < 2; ++mi) {
                n2i[mi] = *(const f32x4*)&n2A[ilo + mi * 16 + quad * 4];
                bi[mi]  = *(const f32x4*)&bA2[ilo + mi * 16 + quad * 4];
            }
            float n2j[2], bj[2];
            #pragma unroll
            for (int ni = 0; ni < 2; ++ni) {
                n2j[ni] = n2B[jlo + ni * 16 + lr];
                bj[ni]  = bB2[jlo + ni * 16 + lr];
            }

            // C/D layout: col = lane&15, row = quad*4 + reg
            #pragma unroll
            for (int mi = 0; mi < 2; ++mi)
                #pragma unroll
                for (int ni = 0; ni < 2; ++ni) {
                    const f32x4 d = acc[mi][ni];
                    #pragma unroll
                    for (int pr = 0; pr < 2; ++pr) {
                        f32x2 d2 = { d[2 * pr], d[2 * pr + 1] };
                        f32x2 t2 = { n2i[mi][2 * pr] + n2j[ni], n2i[mi][2 * pr + 1] + n2j[ni] };
                        f32x2 sq2 = d2 * -2.0f + t2;
                        f32x2 z2 = { 0.f, 0.f };
                        f32x2 mx2 = __builtin_elementwise_max(sq2, z2);
                        float s0 = fast_sqrtf(mx2[0]);
                        float s1 = fast_sqrtf(mx2[1]);
                        f32x2 bs2 = { bi[mi][2 * pr] + bj[ni], bi[mi][2 * pr + 1] + bj[ni] };
                        f32x2 sr2 = { s0, s1 };
                        f32x2 ar2 = sr2 * -L2E + bs2;
                        float e0 = fast_exp2f(ar2[0]);
                        float e1 = fast_exp2f(ar2[1]);
                        if (cls == 0) {
                            f32x2 e2 = { e0, e1 };
                            lacc += e2;
                        } else {
                            const int ig0 = ilo + mi * 16 + quad * 4 + 2 * pr;
                            const int jg = jlo + ni * 16 + lr;
                            if (jg > ig0)     lacc[0] += e0;
                            if (jg > ig0 + 1) lacc[1] += e1;
                        }
                    }
                }
        }

        if (!more) break;
        __syncthreads();                 // staged tile ready (vmcnt drained)
    }

    lsum += lacc[0] + lacc[1];
    #pragma unroll
    for (int m = 32; m >= 1; m >>= 1) lsum += __shfl_xor(lsum, m, 64);
    if (lane == 0) smr[w] = lsum;
    __syncthreads();
    if (tid == 0) {
        float ssum = 0.f;
        #pragma unroll
        for (int i = 0; i < 16; ++i) ssum += smr[i];
        pgemm[b] = ssum;
        // release the partial, then count in (agent scope)
        unsigned prev = __hip_atomic_fetch_add(ctr, 1u, __ATOMIC_ACQ_REL,
                                               __HIP_MEMORY_SCOPE_AGENT);
        lastflag = (prev == N_BLK - 1) ? 1 : 0;
    }
    __syncthreads();

    if (lastflag) {
        // last block: deterministic fixed-order reduction of N_BLK partials
        float v = 0.f;
        if (tid < N_BLK)
            v = __hip_atomic_load(&pgemm[tid], __ATOMIC_RELAXED,
                                  __HIP_MEMORY_SCOPE_AGENT);
        #pragma unroll
        for (int m = 32; m >= 1; m >>= 1) v += __shfl_xor(v, m, 64);
        if (lane == 0) smr[w] = v;
        __syncthreads();
        if (tid == 0) {
            float tsum = 0.f;
            #pragma unroll
            for (int i = 0; i < 16; ++i) tsum += smr[i];
            out[0] = tsum;
        }
    }
}

extern "C" void kernel_launch(void* const* d_in, const int* in_sizes, int n_in,
                              void* d_out, int out_size, void* d_ws, size_t ws_size,
                              hipStream_t stream) {
    const int* edges = (const int*)d_in[0];
    const int* nodes_p_star = (const int*)d_in[1];
    const int* nodes_p = (const int*)d_in[2];
    const float* beta_p = (const float*)d_in[3];
    const float* beta_p_star = (const float*)d_in[4];
    const float* p = (const float*)d_in[5];
    const float* p_star = (const float*)d_in[6];

    char* ws = (char*)d_ws;
    float* pgemm = (float*)(ws + OFF_PGEMM);
    unsigned* ctr = (unsigned*)(ws + OFF_CTR);
    _Float16* psh = (_Float16*)(ws + OFF_PSH);
    _Float16* pph = (_Float16*)(ws + OFF_PPH);
    float* n2s = (float*)(ws + OFF_N2S);
    float* n2p = (float*)(ws + OFF_N2P);
    float* bps2 = (float*)(ws + OFF_BPS);
    float* bp2 = (float*)(ws + OFF_BP);

    prep_kernel<<<4096, 256, 0, stream>>>(
        p, p_star, beta_p, beta_p_star, nodes_p_star, nodes_p,
        psh, n2s, bps2, pph, n2p, bp2, ctr);

    main_kernel<<<N_BLK, 1024, 0, stream>>>(
        psh, pph, n2s, n2p, bps2, bp2,
        edges, beta_p, beta_p_star, p, p_star,
        pgemm, ctr, (float*)d_out);
}